// Round 3
// baseline (322.846 us; speedup 1.0000x reference)
//
#include <hip/hip_runtime.h>
#include <math.h>

#define NPROJ 96
#define NANG  96
#define DET   192
#define NPIX  16384            // 128*128
#define SLICE (NANG*DET)       // 18432

// DSD/DU = DSD/DV = 1000/3.5
#define KPROJ 285.7142857142857f
#define PITCH 132              // LDS row pitch (floats): breaks stride-128 bank aliasing
#define BROWS 22               // max v-window rows for z-chunk 8 is 21
#define ACH   16               // bp2d angle chunk

__device__ __forceinline__ float frcp(float x) { return __builtin_amdgcn_rcpf(x); }

// ---------------------------------------------------------------------------
// K1: fused (sino*weight -> detector gradient -> 2D backprojection -> cosine
// weighting). grid (96 p, 16 pixel-chunks), block 256, 4 px/thread.
// Angles staged in chunks of 16: ws buffer (product) + dv buffer (gradient),
// 24.6 KB LDS -> 6 blocks/CU. pos always in [5.7,185.3] -> no masks.
// ---------------------------------------------------------------------------
__global__ __launch_bounds__(256) void k_bp2d(const float* __restrict__ sino,
                                              const float* __restrict__ wgt,
                                              float* __restrict__ wcb) {
    __shared__ float ws[ACH * DET];    // 12288 B  (sino*weight chunk)
    __shared__ float dv[ACH * DET];    // 12288 B  (gradient chunk)
    __shared__ float sc[NANG], ss[NANG];
    const int p   = blockIdx.x;
    const int tid = threadIdx.x;

    if (tid < NANG) {
        float s_, c_;
        sincosf((float)tid * (float)(3.14159265358979323846 / 96.0), &s_, &c_);
        sc[tid] = c_; ss[tid] = s_;
    }

    const int pixbase = blockIdx.y * 1024;
    float acc[4], fx[4], fy[4];
    #pragma unroll
    for (int i = 0; i < 4; ++i) {
        const int pix = pixbase + i*256 + tid;
        fx[i] = (float)(pix & 127) - 63.5f;
        fy[i] = (float)(pix >> 7)  - 63.5f;
        acc[i] = 0.0f;
    }

    // gradient thread mapping: 16 rows x 192 cols = 3072 = 256 threads x 12
    const int gla = tid >> 4;           // row 0..15
    const int gd0 = (tid & 15) * 12;    // col base 0..180
    __syncthreads();                    // trig ready

    for (int c = 0; c < NANG/ACH; ++c) {
        // ---- stage product chunk: 768 float4, 3 per thread ----
        {
            const float4* s4 = (const float4*)(sino + p * SLICE + c * (ACH*DET));
            const float4* w4 = (const float4*)(wgt  + p * SLICE + c * (ACH*DET));
            float4* dst = (float4*)ws;
            #pragma unroll
            for (int i = 0; i < 3; ++i) {
                const int idx = tid + i*256;
                const float4 a = s4[idx], b = w4[idx];
                dst[idx] = make_float4(a.x*b.x, a.y*b.y, a.z*b.z, a.w*b.w);
            }
        }
        __syncthreads();
        // ---- gradient along detector dim (exact left/mid/right formulas) ----
        {
            const float* r = ws + gla * DET;
            float v[14];
            #pragma unroll
            for (int j = 0; j < 14; ++j) {
                int dd = gd0 - 1 + j;
                dd = (dd < 0) ? 0 : ((dd > DET-1) ? DET-1 : dd);
                v[j] = r[dd];
            }
            float* o = dv + gla * DET + gd0;
            #pragma unroll
            for (int j = 0; j < 12; ++j) {
                const int d = gd0 + j;
                float g = 0.5f * (v[j+2] - v[j]);
                if (d == 0)       g = v[2]  - v[1];    // ws[1]-ws[0]
                if (d == DET-1)   g = v[12] - v[11];   // ws[191]-ws[190]
                o[j] = g;
            }
        }
        __syncthreads();
        // ---- backproject 16 angles ----
        for (int la = 0; la < ACH; ++la) {
            const int a = c * ACH + la;
            const float cb = sc[a], sb = ss[a];
            const float* rowp = dv + la * DET;
            #pragma unroll
            for (int i = 0; i < 4; ++i) {
                const float pos = cb * fx[i] + sb * fy[i] + 95.5f;
                const int   i0  = (int)pos;          // pos > 0 always
                const float f   = pos - (float)i0;
                const float g0  = rowp[i0];
                const float g1  = rowp[i0 + 1];
                acc[i] += fmaf(f, g1 - g0, g0);
            }
        }
        __syncthreads();
    }

    #pragma unroll
    for (int i = 0; i < 4; ++i) {
        const int pix = pixbase + i*256 + tid;
        const float w = 1000.0f * rsqrtf(1000000.0f + fx[i]*fx[i] + fy[i]*fy[i]);
        wcb[p * NPIX + pix] = acc[i] * w;
    }
}

// ---------------------------------------------------------------------------
// K2: 3D cone-beam backprojection + PReLU.
// grid (64 y-pairs, 16 z-chunks), block 256: thread = (x, y-pair), 8 z's.
// Double-buffered LDS row window (<=21 rows, pitch 132): prefetch beta b+1
// into registers while computing beta b -> ONE barrier per beta, L2 latency
// hidden under compute. pu in [11,116], pv in [19,108] -> no masks.
// ---------------------------------------------------------------------------
__global__ __launch_bounds__(256) void k_bp3d(const float* __restrict__ wcb,
                                              const float* __restrict__ prelu,
                                              float* __restrict__ out) {
    __shared__ float sp[2][BROWS * PITCH];   // 23232 B
    __shared__ float sc[NPROJ], ss[NPROJ];
    const int tid = threadIdx.x;
    const int x   = tid & 127;
    const int y   = (blockIdx.x << 1) | (tid >> 7);
    const int z0  = blockIdx.y << 3;

    if (tid < NPROJ) {
        float s_, c_;
        sincosf((float)tid * (float)(2.0 * 3.14159265358979323846 / 96.0), &s_, &c_);
        sc[tid] = c_; ss[tid] = s_;
    }

    const float fx  = (float)x - 63.5f;
    const float fy  = (float)y - 63.5f;
    const float zlo = (float)z0 - 63.5f;
    const float zhi = zlo + 7.0f;

    // v-window for this z-chunk: pv = 63.5 + K*z', K in [0.4844, 0.6966]
    const float KMIN = 0.4843f, KMAX = 0.6967f;
    const float c0 = KMIN * zlo, c1 = KMAX * zlo, c2 = KMIN * zhi, c3 = KMAX * zhi;
    const float mn = fminf(fminf(c0, c1), fminf(c2, c3));
    const float mx = fmaxf(fmaxf(c0, c1), fmaxf(c2, c3));
    int vlo = (int)floorf(63.5f + mn) - 1;
    int vhi = (int)floorf(63.5f + mx) + 2;
    if (vlo < 0)   vlo = 0;
    if (vhi > 127) vhi = 127;
    const int nrow4 = (vhi - vlo + 1) << 5;  // rows * 32 float4/row, <= 672
    const int vloP  = vlo * PITCH;

    // staging slots: thread handles float4 slots tid, tid+256, tid+512
    int  goff[3], loff[3];
    bool vld[3];
    #pragma unroll
    for (int s = 0; s < 3; ++s) {
        const int i = tid + (s << 8);
        vld[s] = (i < nrow4);
        const int row = i >> 5, c4 = i & 31;
        goff[s] = (row << 7) + (c4 << 2);
        loff[s] = row * PITCH + (c4 << 2);
    }
    const float* srcb = wcb + (vlo << 7);

    float acc[8];
    #pragma unroll
    for (int j = 0; j < 8; ++j) acc[j] = 0.0f;

    // initial stage: beta 0 -> buffer 0
    float4 r[3];
    #pragma unroll
    for (int s = 0; s < 3; ++s) if (vld[s]) r[s] = *(const float4*)(srcb + goff[s]);
    #pragma unroll
    for (int s = 0; s < 3; ++s) if (vld[s]) *(float4*)(&sp[0][loff[s]]) = r[s];
    __syncthreads();   // staging + trig ready

    int cur = 0;
    for (int b = 0; b < NPROJ; ++b) {
        // prefetch beta b+1 into registers (hidden under compute below)
        if (b + 1 < NPROJ) {
            const float* nsrc = srcb + (b + 1) * NPIX;
            #pragma unroll
            for (int s = 0; s < 3; ++s) if (vld[s]) r[s] = *(const float4*)(nsrc + goff[s]);
        }

        const float cb    = sc[b], sb = ss[b];
        const float t     = fmaf(fx, cb,  fy * sb);
        const float sdist = fmaf(fy, cb, -fx * sb);
        const float invr  = frcp(500.0f + t);
        const float pu    = fmaf(KPROJ * sdist, invr, 63.5f);
        const int   iu0   = (int)pu;             // pu in [11, 116]
        const float fu    = pu - (float)iu0;
        float w2 = 1000.0f * invr; w2 *= w2;
        const float Kz    = KPROJ * invr;
        const int   cbase = iu0 - vloP;
        const float* spc  = sp[cur];

        #pragma unroll
        for (int j = 0; j < 8; ++j) {
            const float pv  = fmaf(Kz, zlo + (float)j, 63.5f);
            const int   iv0 = (int)pv;           // pv in [19, 108]
            const float fv  = pv - (float)iv0;
            const int   off = iv0 * PITCH + cbase;
            const float g00 = spc[off],         g01 = spc[off + 1];
            const float g10 = spc[off + PITCH], g11 = spc[off + PITCH + 1];
            const float top = fmaf(fu, g01 - g00, g00);
            const float bot = fmaf(fu, g11 - g10, g10);
            acc[j] = fmaf(fmaf(fv, bot - top, top), w2, acc[j]);
        }

        // write prefetched beta b+1 into the other buffer
        if (b + 1 < NPROJ) {
            float* spn = (float*)sp[cur ^ 1];
            #pragma unroll
            for (int s = 0; s < 3; ++s) if (vld[s]) *(float4*)(&spn[loff[s]]) = r[s];
        }
        __syncthreads();   // single barrier per beta
        cur ^= 1;
    }

    const float a = prelu[0];
    #pragma unroll
    for (int j = 0; j < 8; ++j) {
        const float v = acc[j];
        out[((z0 + j) << 14) + (y << 7) + x] = (v >= 0.0f) ? v : a * v;
    }
}

// ---------------------------------------------------------------------------
extern "C" void kernel_launch(void* const* d_in, const int* in_sizes, int n_in,
                              void* d_out, int out_size, void* d_ws, size_t ws_size,
                              hipStream_t stream) {
    const float* sino  = (const float*)d_in[0];   // (1,1,96,96,192)
    const float* wgt   = (const float*)d_in[1];   // (1,96,96,192)
    const float* prelu = (const float*)d_in[2];   // (1,)
    float* wcb = (float*)d_ws;                    // 96*128*128 floats
    float* out = (float*)d_out;                   // 128^3 floats

    k_bp2d<<<dim3(NPROJ, 16), dim3(256), 0, stream>>>(sino, wgt, wcb);
    k_bp3d<<<dim3(64, 16),    dim3(256), 0, stream>>>(wcb, prelu, out);
}

// Round 4
// 318.168 us; speedup vs baseline: 1.0147x; 1.0147x over previous
//
#include <hip/hip_runtime.h>
#include <math.h>

#define NPROJ 96
#define NANG  96
#define DET   192
#define NPIX  16384            // 128*128
#define SLICE (NANG*DET)       // 18432

// DSD/DU = DSD/DV = 1000/3.5
#define KPROJ 285.7142857142857f

__device__ __forceinline__ float frcp(float x) { return __builtin_amdgcn_rcpf(x); }

// ---------------------------------------------------------------------------
// K1: deriv = grad_lastdim(sino * weight), rows of 192 along detector dim
// ---------------------------------------------------------------------------
__global__ __launch_bounds__(192) void k_deriv(const float* __restrict__ sino,
                                               const float* __restrict__ wgt,
                                               float* __restrict__ deriv) {
    __shared__ float row[DET];
    const int r = blockIdx.x;          // p*96 + a, 0..9215
    const int d = threadIdx.x;         // 0..191
    const int base = r * DET + d;
    row[d] = sino[base] * wgt[base];
    __syncthreads();
    float g;
    if (d == 0)           g = row[1] - row[0];
    else if (d == DET-1)  g = row[DET-1] - row[DET-2];
    else                  g = 0.5f * (row[d+1] - row[d-1]);
    deriv[base] = g;
}

// ---------------------------------------------------------------------------
// K2: 2D backprojection + cosine weighting — NO LDS staging, NO barriers.
// grid (96 p, 16 pixel-chunks), block 256, 4 px/thread. Per angle, the
// 192-float deriv row is L1/L2-resident; lanes read ~64-float spans ->
// coalesced. pos always in [5.7,185.3] -> no masks; i0+1 <= 186 < 192.
// ---------------------------------------------------------------------------
__global__ __launch_bounds__(256) void k_bp2d(const float* __restrict__ deriv,
                                              float* __restrict__ wcb) {
    __shared__ float sc[NANG], ss[NANG];
    const int p   = blockIdx.x;
    const int tid = threadIdx.x;

    if (tid < NANG) {
        float s_, c_;
        sincosf((float)tid * (float)(3.14159265358979323846 / 96.0), &s_, &c_);
        sc[tid] = c_; ss[tid] = s_;
    }

    const int pixbase = blockIdx.y * 1024;
    float acc[4], fx[4], fy[4];
    #pragma unroll
    for (int i = 0; i < 4; ++i) {
        const int pix = pixbase + i*256 + tid;
        fx[i] = (float)(pix & 127) - 63.5f;
        fy[i] = (float)(pix >> 7)  - 63.5f;
        acc[i] = 0.0f;
    }
    __syncthreads();   // trig ready — the only barrier

    const float* slice = deriv + p * SLICE;
    for (int a = 0; a < NANG; ++a) {
        const float cb = sc[a], sb = ss[a];
        const float* rowp = slice + a * DET;
        #pragma unroll
        for (int i = 0; i < 4; ++i) {
            const float pos = fmaf(cb, fx[i], fmaf(sb, fy[i], 95.5f));
            const int   i0  = (int)pos;          // pos > 0 always
            const float f   = pos - (float)i0;
            const float g0  = rowp[i0];
            const float g1  = rowp[i0 + 1];
            acc[i] += fmaf(f, g1 - g0, g0);
        }
    }

    #pragma unroll
    for (int i = 0; i < 4; ++i) {
        const int pix = pixbase + i*256 + tid;
        const float w = 1000.0f * rsqrtf(1000000.0f + fx[i]*fx[i] + fy[i]*fy[i]);
        wcb[p * NPIX + pix] = acc[i] * w;
    }
}

// ---------------------------------------------------------------------------
// K3: 3D cone-beam backprojection + PReLU — NO LDS staging, NO barriers.
// grid (64 y-pairs, 32 z-chunks) = 2048 blocks = 8 blocks/CU = 100% waves.
// thread = (x, y-in-pair), 4 z's. Per beta: one 64-bit row address, 4 taps
// as global_load_dword with imm offsets 0/4/512/516. Lanes (x-consecutive)
// span ~45 consecutive iu -> 2-3 cache lines per row; wcb is L2-resident.
// pu in [11,116] (iu0+1<=117<128), pv in [19,108] -> no masks.
// ---------------------------------------------------------------------------
__global__ __launch_bounds__(256) void k_bp3d(const float* __restrict__ wcb,
                                              const float* __restrict__ prelu,
                                              float* __restrict__ out) {
    __shared__ float sc[NPROJ], ss[NPROJ];
    const int tid = threadIdx.x;
    const int x   = tid & 127;
    const int y   = (blockIdx.x << 1) | (tid >> 7);
    const int z0  = blockIdx.y << 2;

    if (tid < NPROJ) {
        float s_, c_;
        sincosf((float)tid * (float)(2.0 * 3.14159265358979323846 / 96.0), &s_, &c_);
        sc[tid] = c_; ss[tid] = s_;
    }

    const float fx  = (float)x - 63.5f;
    const float fy  = (float)y - 63.5f;
    const float zlo = (float)z0 - 63.5f;

    float acc[4];
    #pragma unroll
    for (int j = 0; j < 4; ++j) acc[j] = 0.0f;

    __syncthreads();   // trig ready — the only barrier

    for (int b = 0; b < NPROJ; ++b) {
        const float cb    = sc[b], sb = ss[b];
        const float t     = fmaf(fx, cb,  fy * sb);
        const float sdist = fmaf(fy, cb, -fx * sb);
        const float invr  = frcp(500.0f + t);
        const float pu    = fmaf(KPROJ * sdist, invr, 63.5f);
        const int   iu0   = (int)pu;             // pu in [11, 116]
        const float fu    = pu - (float)iu0;
        float w2 = 1000.0f * invr; w2 *= w2;
        const float Kz    = KPROJ * invr;
        const float* base = wcb + b * NPIX + iu0;

        // compute tap addresses for all 4 z first -> 16 loads in flight
        const float* r0p[4];
        float fv[4];
        #pragma unroll
        for (int j = 0; j < 4; ++j) {
            const float pv  = fmaf(Kz, zlo + (float)j, 63.5f);
            const int   iv0 = (int)pv;           // pv in [19, 108]
            fv[j]  = pv - (float)iv0;
            r0p[j] = base + (iv0 << 7);
        }
        float g00[4], g01[4], g10[4], g11[4];
        #pragma unroll
        for (int j = 0; j < 4; ++j) {
            g00[j] = r0p[j][0];   g01[j] = r0p[j][1];
            g10[j] = r0p[j][128]; g11[j] = r0p[j][129];
        }
        #pragma unroll
        for (int j = 0; j < 4; ++j) {
            const float top = fmaf(fu, g01[j] - g00[j], g00[j]);
            const float bot = fmaf(fu, g11[j] - g10[j], g10[j]);
            acc[j] = fmaf(fmaf(fv[j], bot - top, top), w2, acc[j]);
        }
    }

    const float a = prelu[0];
    #pragma unroll
    for (int j = 0; j < 4; ++j) {
        const float v = acc[j];
        out[((z0 + j) << 14) + (y << 7) + x] = (v >= 0.0f) ? v : a * v;
    }
}

// ---------------------------------------------------------------------------
extern "C" void kernel_launch(void* const* d_in, const int* in_sizes, int n_in,
                              void* d_out, int out_size, void* d_ws, size_t ws_size,
                              hipStream_t stream) {
    const float* sino  = (const float*)d_in[0];   // (1,1,96,96,192)
    const float* wgt   = (const float*)d_in[1];   // (1,96,96,192)
    const float* prelu = (const float*)d_in[2];   // (1,)
    float* deriv = (float*)d_ws;                  // 96*96*192 floats
    float* wcb   = deriv + NPROJ * SLICE;         // 96*128*128 floats
    float* out   = (float*)d_out;                 // 128^3 floats

    k_deriv<<<dim3(NPROJ * NANG), dim3(192), 0, stream>>>(sino, wgt, deriv);
    k_bp2d <<<dim3(NPROJ, 16),    dim3(256), 0, stream>>>(deriv, wcb);
    k_bp3d <<<dim3(64, 32),       dim3(256), 0, stream>>>(wcb, prelu, out);
}

// Round 6
// 222.426 us; speedup vs baseline: 1.4515x; 1.4304x over previous
//
#include <hip/hip_runtime.h>
#include <hip/hip_fp16.h>
#include <math.h>

#define NPROJ 96
#define NANG  96
#define DET   192
#define NPIX  16384            // 128*128
#define SLICE (NANG*DET)       // 18432

// DSD/DU = DSD/DV = 1000/3.5
#define KPROJ 285.7142857142857f

__device__ __forceinline__ float frcp(float x) { return __builtin_amdgcn_rcpf(x); }

typedef __fp16 h2 __attribute__((ext_vector_type(2)));

__device__ __forceinline__ unsigned pack2(float a, float b) {
    h2 p = __builtin_amdgcn_cvt_pkrtz(a, b);
    return __builtin_bit_cast(unsigned, p);
}
__device__ __forceinline__ h2 as_h2(unsigned u) { return __builtin_bit_cast(h2, u); }

#if __has_builtin(__builtin_amdgcn_fdot2)
#define FDOT2(a, b, c) __builtin_amdgcn_fdot2((a), (b), (c), false)
#else
__device__ __forceinline__ float FDOT2(h2 a, h2 b, float c) {
    return c + (float)a[0] * (float)b[0] + (float)a[1] * (float)b[1];
}
#endif

// ---------------------------------------------------------------------------
// K1: deriv = grad_lastdim(sino * weight) -> packed fp16 PAIRS:
// derivp[row][d] = half2(g[d], g[d+1])  (4B aligned at every d).
// Each thread computes g[d] and g[d+1] redundantly from the LDS row (no
// second barrier).
// ---------------------------------------------------------------------------
__global__ __launch_bounds__(192) void k_deriv(const float* __restrict__ sino,
                                               const float* __restrict__ wgt,
                                               unsigned* __restrict__ derivp) {
    __shared__ float row[DET];
    const int r = blockIdx.x;          // p*96 + a
    const int d = threadIdx.x;         // 0..191
    const int base = r * DET + d;
    row[d] = sino[base] * wgt[base];
    __syncthreads();
    float g0, g1;
    if (d == 0)            g0 = row[1] - row[0];
    else if (d == DET-1)   g0 = row[DET-1] - row[DET-2];
    else                   g0 = 0.5f * (row[d+1] - row[d-1]);
    if (d >= DET-2)        g1 = (d == DET-1) ? 0.0f : row[DET-1] - row[DET-2];
    else                   g1 = 0.5f * (row[d+2] - row[d]);
    derivp[base] = pack2(g0, g1);
}

// ---------------------------------------------------------------------------
// K2: 2D backprojection + cosine weighting -> packed fp16 pair output.
// grid (96 p, 16 pixel-chunks), block 256, 4 px/thread, barrier-free main
// loop. Per angle-pixel: ONE dword load (both taps) + fdot2 accumulate.
// pos in [5.7,185.3] -> no masks. Epilogue packs (u,u+1) pairs via LDS.
// ---------------------------------------------------------------------------
__global__ __launch_bounds__(256) void k_bp2d(const unsigned* __restrict__ derivp,
                                              unsigned* __restrict__ wcbp) {
    __shared__ float sc[NANG], ss[NANG];
    __shared__ float buf[1024];
    const int p   = blockIdx.x;
    const int tid = threadIdx.x;

    if (tid < NANG) {
        float s_, c_;
        sincosf((float)tid * (float)(3.14159265358979323846 / 96.0), &s_, &c_);
        sc[tid] = c_; ss[tid] = s_;
    }

    const int pixbase = blockIdx.y * 1024;
    float acc[4], fx[4], fy[4];
    #pragma unroll
    for (int i = 0; i < 4; ++i) {
        const int pix = pixbase + i*256 + tid;
        fx[i] = (float)(pix & 127) - 63.5f;
        fy[i] = (float)(pix >> 7)  - 63.5f;
        acc[i] = 0.0f;
    }
    __syncthreads();   // trig ready

    const unsigned* slice = derivp + p * SLICE;
    for (int a = 0; a < NANG; ++a) {
        const float cb = sc[a], sb = ss[a];
        const unsigned* rowp = slice + a * DET;
        #pragma unroll
        for (int i = 0; i < 4; ++i) {
            const float pos = fmaf(cb, fx[i], fmaf(sb, fy[i], 95.5f));
            const int   i0  = (int)pos;          // pos > 0 always
            const float f   = pos - (float)i0;
            const h2    g   = as_h2(rowp[i0]);   // (deriv[i0], deriv[i0+1])
            const h2    w   = as_h2(pack2(1.0f - f, f));
            acc[i] = FDOT2(g, w, acc[i]);
        }
    }

    // cosine-weight, then pack (u, u+1) pairs via LDS
    #pragma unroll
    for (int i = 0; i < 4; ++i) {
        const float w = 1000.0f * rsqrtf(1000000.0f + fx[i]*fx[i] + fy[i]*fy[i]);
        buf[i*256 + tid] = acc[i] * w;
    }
    __syncthreads();
    #pragma unroll
    for (int i = 0; i < 4; ++i) {
        const int l   = i*256 + tid;
        const int pix = pixbase + l;
        const int u   = pix & 127;
        const float v0 = buf[l];
        const float v1 = (u < 127) ? buf[l + 1] : 0.0f;   // u=127 pair unused
        wcbp[p * NPIX + pix] = pack2(v0, v1);
    }
}

// ---------------------------------------------------------------------------
// K3: 3D cone-beam backprojection + PReLU — barrier-free, fp16-pair taps.
// grid (64 y-pairs, 32 z-chunks) = 2048 blocks = 8 blocks/CU.
// thread = (x, y-in-pair), 4 z's. Per beta per z: TWO dword loads
// (rows iv0, iv0+1; second at imm offset 512B) + 2 fdot2.
// pu in [11,116], pv in [19,108] -> no masks.
// ---------------------------------------------------------------------------
__global__ __launch_bounds__(256) void k_bp3d(const unsigned* __restrict__ wcbp,
                                              const float* __restrict__ prelu,
                                              float* __restrict__ out) {
    __shared__ float sc[NPROJ], ss[NPROJ];
    const int tid = threadIdx.x;
    const int x   = tid & 127;
    const int y   = (blockIdx.x << 1) | (tid >> 7);
    const int z0  = blockIdx.y << 2;

    if (tid < NPROJ) {
        float s_, c_;
        sincosf((float)tid * (float)(2.0 * 3.14159265358979323846 / 96.0), &s_, &c_);
        sc[tid] = c_; ss[tid] = s_;
    }

    const float fx  = (float)x - 63.5f;
    const float fy  = (float)y - 63.5f;
    const float zlo = (float)z0 - 63.5f;

    float acc[4];
    #pragma unroll
    for (int j = 0; j < 4; ++j) acc[j] = 0.0f;

    __syncthreads();   // trig ready — the only barrier

    for (int b = 0; b < NPROJ; ++b) {
        const float cb    = sc[b], sb = ss[b];
        const float t     = fmaf(fx, cb,  fy * sb);
        const float sdist = fmaf(fy, cb, -fx * sb);
        const float invr  = frcp(500.0f + t);
        const float pu    = fmaf(KPROJ * sdist, invr, 63.5f);
        const int   iu0   = (int)pu;             // pu in [11, 116]
        const float fu    = pu - (float)iu0;
        float w2 = 1000.0f * invr; w2 *= w2;
        const float Kz    = KPROJ * invr;
        const float c0    = (1.0f - fu) * w2;    // weight for u tap 0
        const float c1    = fu * w2;             // weight for u tap 1
        const unsigned* base = wcbp + b * NPIX + iu0;

        // addresses + fv for all 4 z first -> 8 loads in flight
        const unsigned* rp[4];
        float fv[4];
        #pragma unroll
        for (int j = 0; j < 4; ++j) {
            const float pv  = fmaf(Kz, zlo + (float)j, 63.5f);
            const int   iv0 = (int)pv;           // pv in [19, 108]
            fv[j]  = pv - (float)iv0;
            rp[j]  = base + (iv0 << 7);
        }
        unsigned g0[4], g1[4];
        #pragma unroll
        for (int j = 0; j < 4; ++j) {
            g0[j] = rp[j][0];        // row iv0:   (g00, g01)
            g1[j] = rp[j][128];      // row iv0+1: (g10, g11)  (+512B imm)
        }
        #pragma unroll
        for (int j = 0; j < 4; ++j) {
            const float fvj = fv[j], ofv = 1.0f - fvj;
            const h2 w0 = as_h2(pack2(ofv * c0, ofv * c1));
            const h2 w1 = as_h2(pack2(fvj * c0, fvj * c1));
            acc[j] = FDOT2(as_h2(g1[j]), w1, FDOT2(as_h2(g0[j]), w0, acc[j]));
        }
    }

    const float a = prelu[0];
    #pragma unroll
    for (int j = 0; j < 4; ++j) {
        const float v = acc[j];
        out[((z0 + j) << 14) + (y << 7) + x] = (v >= 0.0f) ? v : a * v;
    }
}

// ---------------------------------------------------------------------------
extern "C" void kernel_launch(void* const* d_in, const int* in_sizes, int n_in,
                              void* d_out, int out_size, void* d_ws, size_t ws_size,
                              hipStream_t stream) {
    const float* sino  = (const float*)d_in[0];   // (1,1,96,96,192)
    const float* wgt   = (const float*)d_in[1];   // (1,96,96,192)
    const float* prelu = (const float*)d_in[2];   // (1,)
    unsigned* derivp = (unsigned*)d_ws;           // 96*96*192 packed pairs
    unsigned* wcbp   = derivp + NPROJ * SLICE;    // 96*128*128 packed pairs
    float* out = (float*)d_out;                   // 128^3 floats

    k_deriv<<<dim3(NPROJ * NANG), dim3(192), 0, stream>>>(sino, wgt, derivp);
    k_bp2d <<<dim3(NPROJ, 16),    dim3(256), 0, stream>>>(derivp, wcbp);
    k_bp3d <<<dim3(64, 32),       dim3(256), 0, stream>>>(wcbp, prelu, out);
}

// Round 7
// 209.666 us; speedup vs baseline: 1.5398x; 1.0609x over previous
//
#include <hip/hip_runtime.h>
#include <hip/hip_fp16.h>
#include <math.h>

#define NPROJ 96
#define NANG  96
#define DET   192
#define NPIX  16384            // 128*128
#define SLICE (NANG*DET)       // 18432

// DSD/DU = DSD/DV = 1000/3.5
#define KPROJ 285.7142857142857f

__device__ __forceinline__ float frcp(float x) { return __builtin_amdgcn_rcpf(x); }

__device__ __forceinline__ float ffract(float x) {
#if __has_builtin(__builtin_amdgcn_fractf)
    return __builtin_amdgcn_fractf(x);
#else
    return x - floorf(x);
#endif
}

typedef __fp16 h2 __attribute__((ext_vector_type(2)));

__device__ __forceinline__ unsigned pack2(float a, float b) {
    h2 p = __builtin_amdgcn_cvt_pkrtz(a, b);
    return __builtin_bit_cast(unsigned, p);
}
__device__ __forceinline__ h2 as_h2(unsigned u) { return __builtin_bit_cast(h2, u); }

#if __has_builtin(__builtin_amdgcn_fdot2)
#define FDOT2(a, b, c) __builtin_amdgcn_fdot2((a), (b), (c), false)
#else
__device__ __forceinline__ float FDOT2(h2 a, h2 b, float c) {
    return c + (float)a[0] * (float)b[0] + (float)a[1] * (float)b[1];
}
#endif

// ---------------------------------------------------------------------------
// K1: deriv = grad_lastdim(sino * weight) -> packed fp16 PAIRS:
// derivp[row][d] = half2(g[d], g[d+1]).
// ---------------------------------------------------------------------------
__global__ __launch_bounds__(192) void k_deriv(const float* __restrict__ sino,
                                               const float* __restrict__ wgt,
                                               unsigned* __restrict__ derivp) {
    __shared__ float row[DET];
    const int r = blockIdx.x;          // p*96 + a
    const int d = threadIdx.x;         // 0..191
    const int base = r * DET + d;
    row[d] = sino[base] * wgt[base];
    __syncthreads();
    float g0, g1;
    if (d == 0)            g0 = row[1] - row[0];
    else if (d == DET-1)   g0 = row[DET-1] - row[DET-2];
    else                   g0 = 0.5f * (row[d+1] - row[d-1]);
    if (d >= DET-2)        g1 = (d == DET-1) ? 0.0f : row[DET-1] - row[DET-2];
    else                   g1 = 0.5f * (row[d+2] - row[d]);
    derivp[base] = pack2(g0, g1);
}

// ---------------------------------------------------------------------------
// K2: 2D backprojection + cosine weighting -> packed fp16 pair output.
// grid (96 p, 16 pixel-chunks), block 256, 4 px/thread, barrier-free main
// loop. Per angle-pixel: ONE dword load (both taps via 32-bit saddr offset)
// + fract weight + fdot2. pos in [5.7,185.3] -> no masks.
// ---------------------------------------------------------------------------
__global__ __launch_bounds__(256) void k_bp2d(const unsigned* __restrict__ derivp,
                                              unsigned* __restrict__ wcbp) {
    __shared__ float sc[NANG], ss[NANG];
    __shared__ float buf[1024];
    const int p   = blockIdx.x;
    const int tid = threadIdx.x;

    if (tid < NANG) {
        float s_, c_;
        sincosf((float)tid * (float)(3.14159265358979323846 / 96.0), &s_, &c_);
        sc[tid] = c_; ss[tid] = s_;
    }

    const int pixbase = blockIdx.y * 1024;
    float acc[4], fx[4], fy[4];
    #pragma unroll
    for (int i = 0; i < 4; ++i) {
        const int pix = pixbase + i*256 + tid;
        fx[i] = (float)(pix & 127) - 63.5f;
        fy[i] = (float)(pix >> 7)  - 63.5f;
        acc[i] = 0.0f;
    }
    __syncthreads();   // trig ready

    const unsigned* rowp = derivp + p * SLICE;   // advances by DET per angle
    for (int a = 0; a < NANG; ++a, rowp += DET) {
        const float cb = sc[a], sb = ss[a];
        #pragma unroll
        for (int i = 0; i < 4; ++i) {
            const float pos = fmaf(cb, fx[i], fmaf(sb, fy[i], 95.5f));
            const int   i0  = (int)pos;            // pos > 0 always
            const float f   = ffract(pos);
            const h2    g   = as_h2(rowp[i0]);     // (deriv[i0], deriv[i0+1])
            acc[i] = FDOT2(g, as_h2(pack2(1.0f - f, f)), acc[i]);
        }
    }

    // cosine-weight, then pack (u, u+1) pairs via LDS
    #pragma unroll
    for (int i = 0; i < 4; ++i) {
        const float w = 1000.0f * rsqrtf(1000000.0f + fx[i]*fx[i] + fy[i]*fy[i]);
        buf[i*256 + tid] = acc[i] * w;
    }
    __syncthreads();
    #pragma unroll
    for (int i = 0; i < 4; ++i) {
        const int l   = i*256 + tid;
        const int pix = pixbase + l;
        const int u   = pix & 127;
        const float v0 = buf[l];
        const float v1 = (u < 127) ? buf[l + 1] : 0.0f;   // u=127 pair unused
        wcbp[p * NPIX + pix] = pack2(v0, v1);
    }
}

// ---------------------------------------------------------------------------
// K3: 3D cone-beam backprojection + PReLU — barrier-free, fp16-pair taps,
// VALU-diet inner loop:
//  * wu (u-interp weights) packed ONCE per beta (fu is z-invariant)
//  * fu/fv via v_fract_f32
//  * 32-bit offsets from uniform per-beta base (saddr loads, g1 at imm 512)
//  * per z: fma+cvt+fract+lshl_add + 2 loads + 2 fdot2 + sub + 2 fma
// grid (64 y-pairs, 32 z-chunks) = 2048 blocks = 8 blocks/CU.
// pu in [11,116], pv in [19,108] -> no masks.
// ---------------------------------------------------------------------------
__global__ __launch_bounds__(256) void k_bp3d(const unsigned* __restrict__ wcbp,
                                              const float* __restrict__ prelu,
                                              float* __restrict__ out) {
    __shared__ float sc[NPROJ], ss[NPROJ];
    const int tid = threadIdx.x;
    const int x   = tid & 127;
    const int y   = (blockIdx.x << 1) | (tid >> 7);
    const int z0  = blockIdx.y << 2;

    if (tid < NPROJ) {
        float s_, c_;
        sincosf((float)tid * (float)(2.0 * 3.14159265358979323846 / 96.0), &s_, &c_);
        sc[tid] = c_; ss[tid] = s_;
    }

    const float fx  = (float)x - 63.5f;
    const float fy  = (float)y - 63.5f;
    const float zlo = (float)z0 - 63.5f;

    float acc[4];
    #pragma unroll
    for (int j = 0; j < 4; ++j) acc[j] = 0.0f;

    __syncthreads();   // trig ready — the only barrier

    const unsigned* bb = wcbp;           // uniform per-beta base (SGPR)
    for (int b = 0; b < NPROJ; ++b, bb += NPIX) {
        const float cb    = sc[b], sb = ss[b];
        const float t     = fmaf(fx, cb,  fy * sb);
        const float sdist = fmaf(fy, cb, -fx * sb);
        const float invr  = frcp(500.0f + t);
        const float pu    = fmaf(KPROJ * sdist, invr, 63.5f);
        const int   iu0   = (int)pu;             // pu in [11, 116]
        const float fu    = ffract(pu);
        float w2 = 1000.0f * invr; w2 *= w2;
        const float Kz    = KPROJ * invr;
        const h2    wu    = as_h2(pack2(1.0f - fu, fu));   // z-invariant!

        int   off[4];
        float fv[4];
        #pragma unroll
        for (int j = 0; j < 4; ++j) {
            const float pv  = fmaf(Kz, zlo + (float)j, 63.5f);
            const int   iv0 = (int)pv;           // pv in [19, 108]
            fv[j]  = ffract(pv);
            off[j] = (iv0 << 7) + iu0;           // 32-bit element offset
        }
        unsigned g0[4], g1[4];
        #pragma unroll
        for (int j = 0; j < 4; ++j) {
            g0[j] = bb[off[j]];                  // row iv0:   (g00, g01)
            g1[j] = bb[off[j] + 128];            // row iv0+1: imm offset 512B
        }
        #pragma unroll
        for (int j = 0; j < 4; ++j) {
            const float top = FDOT2(as_h2(g0[j]), wu, 0.0f);
            const float bot = FDOT2(as_h2(g1[j]), wu, 0.0f);
            acc[j] = fmaf(fmaf(fv[j], bot - top, top), w2, acc[j]);
        }
    }

    const float a = prelu[0];
    #pragma unroll
    for (int j = 0; j < 4; ++j) {
        const float v = acc[j];
        out[((z0 + j) << 14) + (y << 7) + x] = (v >= 0.0f) ? v : a * v;
    }
}

// ---------------------------------------------------------------------------
extern "C" void kernel_launch(void* const* d_in, const int* in_sizes, int n_in,
                              void* d_out, int out_size, void* d_ws, size_t ws_size,
                              hipStream_t stream) {
    const float* sino  = (const float*)d_in[0];   // (1,1,96,96,192)
    const float* wgt   = (const float*)d_in[1];   // (1,96,96,192)
    const float* prelu = (const float*)d_in[2];   // (1,)
    unsigned* derivp = (unsigned*)d_ws;           // 96*96*192 packed pairs
    unsigned* wcbp   = derivp + NPROJ * SLICE;    // 96*128*128 packed pairs
    float* out = (float*)d_out;                   // 128^3 floats

    k_deriv<<<dim3(NPROJ * NANG), dim3(192), 0, stream>>>(sino, wgt, derivp);
    k_bp2d <<<dim3(NPROJ, 16),    dim3(256), 0, stream>>>(derivp, wcbp);
    k_bp3d <<<dim3(64, 32),       dim3(256), 0, stream>>>(wcbp, prelu, out);
}

// Round 8
// 198.805 us; speedup vs baseline: 1.6239x; 1.0546x over previous
//
#include <hip/hip_runtime.h>
#include <hip/hip_fp16.h>
#include <math.h>

#define NPROJ 96
#define NANG  96
#define DET   192
#define NPIX  16384            // 128*128
#define SLICE (NANG*DET)       // 18432

// DSD/DU = DSD/DV = 1000/3.5
#define KPROJ 285.7142857142857f

__device__ __forceinline__ float frcp(float x) { return __builtin_amdgcn_rcpf(x); }

__device__ __forceinline__ float ffract(float x) {
#if __has_builtin(__builtin_amdgcn_fractf)
    return __builtin_amdgcn_fractf(x);
#else
    return x - floorf(x);
#endif
}

typedef __fp16 h2 __attribute__((ext_vector_type(2)));

__device__ __forceinline__ unsigned pack2(float a, float b) {
    h2 p = __builtin_amdgcn_cvt_pkrtz(a, b);
    return __builtin_bit_cast(unsigned, p);
}
__device__ __forceinline__ h2 as_h2(unsigned u) { return __builtin_bit_cast(h2, u); }

#if __has_builtin(__builtin_amdgcn_fdot2)
#define FDOT2(a, b, c) __builtin_amdgcn_fdot2((a), (b), (c), false)
#else
__device__ __forceinline__ float FDOT2(h2 a, h2 b, float c) {
    return c + (float)a[0] * (float)b[0] + (float)a[1] * (float)b[1];
}
#endif

// ---------------------------------------------------------------------------
// K1: deriv = grad_lastdim(sino * weight) -> packed fp16 PAIRS:
// derivp[row][d] = half2(g[d], g[d+1]).
// ---------------------------------------------------------------------------
__global__ __launch_bounds__(192) void k_deriv(const float* __restrict__ sino,
                                               const float* __restrict__ wgt,
                                               unsigned* __restrict__ derivp) {
    __shared__ float row[DET];
    const int r = blockIdx.x;          // p*96 + a
    const int d = threadIdx.x;         // 0..191
    const int base = r * DET + d;
    row[d] = sino[base] * wgt[base];
    __syncthreads();
    float g0, g1;
    if (d == 0)            g0 = row[1] - row[0];
    else if (d == DET-1)   g0 = row[DET-1] - row[DET-2];
    else                   g0 = 0.5f * (row[d+1] - row[d-1]);
    if (d >= DET-2)        g1 = (d == DET-1) ? 0.0f : row[DET-1] - row[DET-2];
    else                   g1 = 0.5f * (row[d+2] - row[d]);
    derivp[base] = pack2(g0, g1);
}

// ---------------------------------------------------------------------------
// K2: 2D backprojection + cosine weighting -> packed QUAD layout for bp3d:
//   wcb4[p][v][u] = uint2{ half2(w[v][u], w[v][u+1]), half2(w[v+1][u], w[v+1][u+1]) }
// Each pixel's pair is stored twice: as .x of its own row and .y of row v-1.
// grid (96 p, 32 chunks), block 256, 2 px/thread -> 3072 blocks = 12/CU
// (32 waves/CU) for latency hiding. pos in [5.7,185.3] -> no masks.
// ---------------------------------------------------------------------------
__global__ __launch_bounds__(256) void k_bp2d(const unsigned* __restrict__ derivp,
                                              unsigned* __restrict__ wcb4) {
    __shared__ float sc[NANG], ss[NANG];
    __shared__ float buf[512];
    const int p   = blockIdx.x;
    const int tid = threadIdx.x;

    if (tid < NANG) {
        float s_, c_;
        sincosf((float)tid * (float)(3.14159265358979323846 / 96.0), &s_, &c_);
        sc[tid] = c_; ss[tid] = s_;
    }

    const int pixbase = blockIdx.y * 512;
    float acc[2], fx[2], fy[2];
    #pragma unroll
    for (int i = 0; i < 2; ++i) {
        const int pix = pixbase + i*256 + tid;
        fx[i] = (float)(pix & 127) - 63.5f;
        fy[i] = (float)(pix >> 7)  - 63.5f;
        acc[i] = 0.0f;
    }
    __syncthreads();   // trig ready

    const unsigned* rowp = derivp + p * SLICE;   // advances by DET per angle
    for (int a = 0; a < NANG; ++a, rowp += DET) {
        const float cb = sc[a], sb = ss[a];
        #pragma unroll
        for (int i = 0; i < 2; ++i) {
            const float pos = fmaf(cb, fx[i], fmaf(sb, fy[i], 95.5f));
            const int   i0  = (int)pos;            // pos > 0 always
            const float f   = ffract(pos);
            const h2    g   = as_h2(rowp[i0]);     // (deriv[i0], deriv[i0+1])
            acc[i] = FDOT2(g, as_h2(pack2(1.0f - f, f)), acc[i]);
        }
    }

    // cosine-weight, pack (u,u+1) pairs via LDS, dual-store into quad layout
    #pragma unroll
    for (int i = 0; i < 2; ++i) {
        const float w = 1000.0f * rsqrtf(1000000.0f + fx[i]*fx[i] + fy[i]*fy[i]);
        buf[i*256 + tid] = acc[i] * w;
    }
    __syncthreads();
    unsigned* slice4 = wcb4 + p * (NPIX * 2);    // uint2 viewed as 2 dwords
    #pragma unroll
    for (int i = 0; i < 2; ++i) {
        const int l   = i*256 + tid;
        const int pix = pixbase + l;
        const int u   = pix & 127;
        const int v   = pix >> 7;
        const float v0 = buf[l];
        const float v1 = (u < 127) ? buf[l + 1] : 0.0f;   // u=127 pair unused
        const unsigned pr = pack2(v0, v1);
        slice4[pix * 2] = pr;                         // wcb4[v][u].x
        if (v >= 1) slice4[(pix - 128) * 2 + 1] = pr; // wcb4[v-1][u].y
    }
}

// ---------------------------------------------------------------------------
// K3: 3D cone-beam backprojection + PReLU — barrier-free, quad-packed taps:
// ONE dwordx2 load per voxel-beta fetches the full 2x2 stencil.
// grid (64 y-pairs, 32 z-chunks) = 2048 blocks = 8 blocks/CU.
// per z: fma(pv), cvt, fract, lshl_add(byte off), load x2, 2 fdot2, sub, 2 fma.
// pu in [11,116], pv in [19,108] -> no masks; .y of row 127 never read.
// ---------------------------------------------------------------------------
__global__ __launch_bounds__(256) void k_bp3d(const uint2* __restrict__ wcb4,
                                              const float* __restrict__ prelu,
                                              float* __restrict__ out) {
    __shared__ float sc[NPROJ], ss[NPROJ];
    const int tid = threadIdx.x;
    const int x   = tid & 127;
    const int y   = (blockIdx.x << 1) | (tid >> 7);
    const int z0  = blockIdx.y << 2;

    if (tid < NPROJ) {
        float s_, c_;
        sincosf((float)tid * (float)(2.0 * 3.14159265358979323846 / 96.0), &s_, &c_);
        sc[tid] = c_; ss[tid] = s_;
    }

    const float fx  = (float)x - 63.5f;
    const float fy  = (float)y - 63.5f;
    const float zlo = (float)z0 - 63.5f;

    float acc[4];
    #pragma unroll
    for (int j = 0; j < 4; ++j) acc[j] = 0.0f;

    __syncthreads();   // trig ready — the only barrier

    const uint2* bb = wcb4;              // uniform per-beta base (SGPR)
    for (int b = 0; b < NPROJ; ++b, bb += NPIX) {
        const float cb    = sc[b], sb = ss[b];
        const float t     = fmaf(fx, cb,  fy * sb);
        const float sdist = fmaf(fy, cb, -fx * sb);
        const float invr  = frcp(500.0f + t);
        const float pu    = fmaf(KPROJ * sdist, invr, 63.5f);
        const int   iu0   = (int)pu;             // pu in [11, 116]
        const float fu    = ffract(pu);
        float w2 = 1000.0f * invr; w2 *= w2;
        const float Kz    = KPROJ * invr;
        const h2    wu    = as_h2(pack2(1.0f - fu, fu));   // z-invariant

        int   off[4];
        float fv[4];
        #pragma unroll
        for (int j = 0; j < 4; ++j) {
            const float pv  = fmaf(Kz, zlo + (float)j, 63.5f);
            const int   iv0 = (int)pv;           // pv in [19, 108]
            fv[j]  = ffract(pv);
            off[j] = (iv0 << 7) + iu0;           // uint2-element offset
        }
        uint2 g[4];
        #pragma unroll
        for (int j = 0; j < 4; ++j) g[j] = bb[off[j]];   // all 4 taps, 8B
        #pragma unroll
        for (int j = 0; j < 4; ++j) {
            const float top = FDOT2(as_h2(g[j].x), wu, 0.0f);
            const float bot = FDOT2(as_h2(g[j].y), wu, 0.0f);
            acc[j] = fmaf(fmaf(fv[j], bot - top, top), w2, acc[j]);
        }
    }

    const float a = prelu[0];
    #pragma unroll
    for (int j = 0; j < 4; ++j) {
        const float v = acc[j];
        out[((z0 + j) << 14) + (y << 7) + x] = (v >= 0.0f) ? v : a * v;
    }
}

// ---------------------------------------------------------------------------
extern "C" void kernel_launch(void* const* d_in, const int* in_sizes, int n_in,
                              void* d_out, int out_size, void* d_ws, size_t ws_size,
                              hipStream_t stream) {
    const float* sino  = (const float*)d_in[0];   // (1,1,96,96,192)
    const float* wgt   = (const float*)d_in[1];   // (1,96,96,192)
    const float* prelu = (const float*)d_in[2];   // (1,)
    unsigned* derivp = (unsigned*)d_ws;           // 96*96*192 packed pairs
    unsigned* wcb4   = derivp + NPROJ * SLICE;    // 96*128*128 uint2 quads
    float* out = (float*)d_out;                   // 128^3 floats

    k_deriv<<<dim3(NPROJ * NANG), dim3(192), 0, stream>>>(sino, wgt, derivp);
    k_bp2d <<<dim3(NPROJ, 32),    dim3(256), 0, stream>>>(derivp, wcb4);
    k_bp3d <<<dim3(64, 32),       dim3(256), 0, stream>>>((const uint2*)wcb4, prelu, out);
}